// Round 1
// baseline (285.283 us; speedup 1.0000x reference)
//
#include <hip/hip_runtime.h>
#include <math.h>

// DAM (dual attention) fused op on MI355X.
// B=2, C=32, N=4096, fp32.
//
// out = alpha*e_p + beta*e_c + 2*a
//   f    = relu(BN(a))                       [B][C][N]
//   cb   = f^T f (per batch, N x N), s = softmax(cb, axis=1)  (column-norm)
//   e_p[c,m] = sum_n f[c,n] * exp(cb[m,n]-M[n]) / Z[n]
//   aa   = a a^T (32x32), x = softmax over BATCH axis (2 entries)
//   e_c[i,n] = sum_j x[b,j,i] a[b,j,n]
//
// Two-pass column softmax with M-hat = cb[n,n] stabilizer (shift-invariant).

#define BB 2
#define CC 32
#define NN 4096
#define EPSV 1e-5f

// ws layout (float offsets)
#define OFF_FT   0          // f transposed [B][N][C]  (262144)
#define OFF_M    262144     // Mhat[b][n] = ||f_n||^2  (8192)
#define OFF_Z    270336     // Z[b][n] (atomic accum)  (8192)
#define OFF_SC   278528     // BN scale[c]             (32)
#define OFF_SH   278560     // BN shift[c]             (32)
#define OFF_AA   278592     // aa[b][d][c]             (2048)
#define OFF_XW   280640     // xw[b][i][j] = x[b,j,i]  (2048)
#define OFF_EP   282688     // e_p[b][c][n] (atomic)   (262144)
#define WS_FLOATS 544832

// ---------------- Kernel A: BN stats per channel -> scale/shift ----------------
__global__ void k_bnstats(const float* __restrict__ x, const float* __restrict__ gamma,
                          const float* __restrict__ bias, float* __restrict__ ws) {
    const int c = blockIdx.x;
    const int tid = threadIdx.x;
    float s = 0.f, s2 = 0.f;
    for (int i = tid; i < BB * NN; i += 256) {
        const int b = i >> 12, n = i & (NN - 1);
        const float v = x[((size_t)(b * CC + c)) * NN + n];
        s += v; s2 += v * v;
    }
    for (int off = 32; off; off >>= 1) { s += __shfl_down(s, off); s2 += __shfl_down(s2, off); }
    __shared__ float rs[4], rs2[4];
    const int w = tid >> 6, l = tid & 63;
    if (l == 0) { rs[w] = s; rs2[w] = s2; }
    __syncthreads();
    if (tid == 0) {
        const float S = rs[0] + rs[1] + rs[2] + rs[3];
        const float S2 = rs2[0] + rs2[1] + rs2[2] + rs2[3];
        const float mean = S * (1.f / (BB * NN));
        const float var = S2 * (1.f / (BB * NN)) - mean * mean;  // biased (ddof=0)
        const float sc = gamma[c] * rsqrtf(var + EPSV);
        ws[OFF_SC + c] = sc;
        ws[OFF_SH + c] = bias[c] - mean * sc;
    }
}

// ---------------- Kernel B: f = relu(bn(x)), store transposed ft[b][n][c], Mhat ----------------
__global__ void k_makef(const float* __restrict__ x, float* __restrict__ ws) {
    const int idx = blockIdx.x * 128 + threadIdx.x;   // 0..8191 == b*N+n
    const int b = idx >> 12, n = idx & (NN - 1);
    __shared__ float ssc[CC], ssh[CC];
    if (threadIdx.x < CC) { ssc[threadIdx.x] = ws[OFF_SC + threadIdx.x]; ssh[threadIdx.x] = ws[OFF_SH + threadIdx.x]; }
    __syncthreads();
    float msum = 0.f;
    float* ftp = ws + OFF_FT + (size_t)idx * CC;
    #pragma unroll
    for (int c = 0; c < CC; ++c) {
        const float v = x[((size_t)(b * CC + c)) * NN + n];
        const float f = fmaxf(v * ssc[c] + ssh[c], 0.f);
        ftp[c] = f;
        msum += f * f;
    }
    ws[OFF_M + idx] = msum;   // cb[n,n]
}

// ---------------- Kernel C: aa[b][d][c] = sum_n a[b,c,n]*a[b,d,n] ----------------
__global__ void k_aa(const float* __restrict__ x, float* __restrict__ ws) {
    const int bid = blockIdx.x;           // b*32+d
    const int b = bid >> 5, d = bid & 31;
    const int tid = threadIdx.x;
    const float* xb = x + (size_t)b * CC * NN;
    float acc[CC];
    #pragma unroll
    for (int c = 0; c < CC; ++c) acc[c] = 0.f;
    for (int n = tid; n < NN; n += 256) {
        const float vd = xb[(size_t)d * NN + n];
        #pragma unroll
        for (int c = 0; c < CC; ++c) acc[c] += xb[(size_t)c * NN + n] * vd;
    }
    __shared__ float red[4][CC];
    const int w = tid >> 6, l = tid & 63;
    #pragma unroll
    for (int c = 0; c < CC; ++c) {
        float r = acc[c];
        for (int off = 32; off; off >>= 1) r += __shfl_down(r, off);
        if (l == 0) red[w][c] = r;
    }
    __syncthreads();
    if (tid < CC) ws[OFF_AA + ((size_t)(b * CC + d)) * CC + tid] =
        red[0][tid] + red[1][tid] + red[2][tid] + red[3][tid];
}

// ---------------- Kernel C2: batch-axis softmax (B=2) -> xw[b][i][j] = x[b,j,i] ----------------
__global__ void k_xw(float* __restrict__ ws) {
    const int t = threadIdx.x;        // i*32 + j
    const int i = t >> 5, j = t & 31;
    const float a0 = ws[OFF_AA + (0 * CC + j) * CC + i];
    const float a1 = ws[OFF_AA + (1 * CC + j) * CC + i];
    const float mx = fmaxf(a0, a1);   // mandatory: aa ~ O(4096), exp would overflow
    const float e0 = __expf(a0 - mx), e1 = __expf(a1 - mx);
    const float inv = 1.f / (e0 + e1);
    ws[OFF_XW + (0 * CC + i) * CC + j] = e0 * inv;
    ws[OFF_XW + (1 * CC + i) * CC + j] = e1 * inv;
}

// ---------------- Kernel D: pass 1, Z[n] = sum_k exp(cb[k,n]-Mhat[n]) ----------------
// grid 512: b(1) x ntile(16) x kchunk(16); 256 thr, thread owns column n
__global__ void __launch_bounds__(256) k_zpass(float* __restrict__ ws) {
    const int bid = blockIdx.x;
    const int b = bid >> 8;
    const int ntile = (bid >> 4) & 15;
    const int kch = bid & 15;
    const int tid = threadIdx.x;
    const int n = ntile * 256 + tid;

    float own[CC];
    {
        const float4* o4 = (const float4*)(ws + OFF_FT + (size_t)(b * NN + n) * CC);
        #pragma unroll
        for (int q = 0; q < 8; ++q) {
            const float4 v = o4[q];
            own[4*q+0] = v.x; own[4*q+1] = v.y; own[4*q+2] = v.z; own[4*q+3] = v.w;
        }
    }
    const float Mn = ws[OFF_M + b * NN + n];
    float z = 0.f;

    __shared__ float tile[64 * CC];   // 8KB k-tile
    const int k0 = kch * 256;
    for (int kt = 0; kt < 256; kt += 64) {
        __syncthreads();
        const float4* src = (const float4*)(ws + OFF_FT + (size_t)(b * NN + k0 + kt) * CC);
        float4* dst = (float4*)tile;
        dst[tid] = src[tid];
        dst[tid + 256] = src[tid + 256];
        __syncthreads();
        for (int kk = 0; kk < 64; ++kk) {
            const float4* t4 = (const float4*)(tile + kk * CC);  // broadcast reads
            float d0 = 0.f, d1 = 0.f, d2 = 0.f, d3 = 0.f;
            #pragma unroll
            for (int q = 0; q < 8; ++q) {
                const float4 v = t4[q];
                d0 += v.x * own[4*q+0];
                d1 += v.y * own[4*q+1];
                d2 += v.z * own[4*q+2];
                d3 += v.w * own[4*q+3];
            }
            z += __expf((d0 + d1) + (d2 + d3) - Mn);
        }
    }
    atomicAdd(ws + OFF_Z + b * NN + n, z);
}

// ---------------- Kernel E: pass 2, e_p[c,m] += sum_n w(m,n)*f[c,n] ----------------
// grid 512: b(1) x mtile(16) x nchunk(16); thread owns output column m
__global__ void __launch_bounds__(256) k_eppass(float* __restrict__ ws) {
    const int bid = blockIdx.x;
    const int b = bid >> 8;
    const int mtile = (bid >> 4) & 15;
    const int nch = bid & 15;
    const int tid = threadIdx.x;
    const int m = mtile * 256 + tid;

    float own[CC], acc[CC];
    {
        const float4* o4 = (const float4*)(ws + OFF_FT + (size_t)(b * NN + m) * CC);
        #pragma unroll
        for (int q = 0; q < 8; ++q) {
            const float4 v = o4[q];
            own[4*q+0] = v.x; own[4*q+1] = v.y; own[4*q+2] = v.z; own[4*q+3] = v.w;
        }
    }
    #pragma unroll
    for (int c = 0; c < CC; ++c) acc[c] = 0.f;

    __shared__ float tile[64 * CC];
    __shared__ float sM[64], sZi[64];
    const int n0 = nch * 256;
    for (int nt = 0; nt < 256; nt += 64) {
        __syncthreads();
        const float4* src = (const float4*)(ws + OFF_FT + (size_t)(b * NN + n0 + nt) * CC);
        float4* dst = (float4*)tile;
        dst[tid] = src[tid];
        dst[tid + 256] = src[tid + 256];
        if (tid < 64)       sM[tid]       = ws[OFF_M + b * NN + n0 + nt + tid];
        else if (tid < 128) sZi[tid - 64] = 1.0f / ws[OFF_Z + b * NN + n0 + nt + tid - 64];
        __syncthreads();
        for (int nn = 0; nn < 64; ++nn) {
            const float4* t4 = (const float4*)(tile + nn * CC);
            float4 v[8];
            float d0 = 0.f, d1 = 0.f, d2 = 0.f, d3 = 0.f;
            #pragma unroll
            for (int q = 0; q < 8; ++q) {
                v[q] = t4[q];
                d0 += v[q].x * own[4*q+0];
                d1 += v[q].y * own[4*q+1];
                d2 += v[q].z * own[4*q+2];
                d3 += v[q].w * own[4*q+3];
            }
            const float w = __expf((d0 + d1) + (d2 + d3) - sM[nn]) * sZi[nn];
            #pragma unroll
            for (int q = 0; q < 8; ++q) {
                acc[4*q+0] += w * v[q].x;
                acc[4*q+1] += w * v[q].y;
                acc[4*q+2] += w * v[q].z;
                acc[4*q+3] += w * v[q].w;
            }
        }
    }
    #pragma unroll
    for (int c = 0; c < CC; ++c)
        atomicAdd(ws + OFF_EP + ((size_t)(b * CC + c)) * NN + m, acc[c]);
}

// ---------------- Kernel F: out = alpha*e_p + beta*e_c + 2a ----------------
__global__ void k_final(const float* __restrict__ x, const float* __restrict__ alpha_p,
                        const float* __restrict__ beta_p, const float* __restrict__ ws,
                        float* __restrict__ out) {
    const int idx = blockIdx.x * 128 + threadIdx.x;  // b*N + m
    const int b = idx >> 12, m = idx & (NN - 1);
    __shared__ float sxw[CC * CC];
    for (int i = threadIdx.x; i < CC * CC; i += 128)
        sxw[i] = ws[OFF_XW + b * CC * CC + i];
    __syncthreads();
    const float alpha = *alpha_p, beta = *beta_p;
    float ec[CC];
    #pragma unroll
    for (int c = 0; c < CC; ++c) ec[c] = 0.f;
    const float* xb = x + (size_t)b * CC * NN;
    #pragma unroll
    for (int j = 0; j < CC; ++j) {
        const float aj = xb[(size_t)j * NN + m];
        #pragma unroll
        for (int c = 0; c < CC; ++c) ec[c] += sxw[c * CC + j] * aj;  // broadcast LDS
    }
    #pragma unroll
    for (int c = 0; c < CC; ++c) {
        const float av = xb[(size_t)c * NN + m];
        out[((size_t)(b * CC + c)) * NN + m] =
            alpha * ws[OFF_EP + ((size_t)(b * CC + c)) * NN + m] + beta * ec[c] + 2.f * av;
    }
}

extern "C" void kernel_launch(void* const* d_in, const int* in_sizes, int n_in,
                              void* d_out, int out_size, void* d_ws, size_t ws_size,
                              hipStream_t stream) {
    const float* x     = (const float*)d_in[0];
    const float* gamma = (const float*)d_in[1];
    const float* bias  = (const float*)d_in[2];
    const float* alpha = (const float*)d_in[3];
    const float* beta  = (const float*)d_in[4];
    float* out = (float*)d_out;
    float* ws  = (float*)d_ws;

    // zero ws (Z and e_p are atomic accumulation targets; harness poisons ws)
    hipMemsetAsync(d_ws, 0, (size_t)WS_FLOATS * sizeof(float), stream);

    hipLaunchKernelGGL(k_bnstats, dim3(32),  dim3(256), 0, stream, x, gamma, bias, ws);
    hipLaunchKernelGGL(k_makef,   dim3(64),  dim3(128), 0, stream, x, ws);
    hipLaunchKernelGGL(k_aa,      dim3(64),  dim3(256), 0, stream, x, ws);
    hipLaunchKernelGGL(k_xw,      dim3(1),   dim3(1024),0, stream, ws);
    hipLaunchKernelGGL(k_zpass,   dim3(512), dim3(256), 0, stream, ws);
    hipLaunchKernelGGL(k_eppass,  dim3(512), dim3(256), 0, stream, ws);
    hipLaunchKernelGGL(k_final,   dim3(64),  dim3(128), 0, stream, x, alpha, beta, ws, out);
}

// Round 2
// 140.886 us; speedup vs baseline: 2.0249x; 2.0249x over previous
//
#include <hip/hip_runtime.h>
#include <math.h>

// DAM (dual attention) on MI355X — MFMA version.
// B=2, C=32, N=4096, fp32 in/out; internal bf16 for the two N^2 passes.
//
// out = alpha*e_p + beta*e_c + 2*a
//   f = relu(BN(a));  cb[n,m] = sum_c f[c,n]f[c,m]  (symmetric)
//   w[m,n] = exp(cb[m,n]-M[n]) / Z[n],  Z[n] = sum_k exp(cb[k,n]-M[n]),  M[n]=cb[n,n]
//   e_p[c,m] = sum_n f[c,n] w[m,n]
//   aa = a a^T (32x32), x = softmax over batch axis; e_c[i,n] = sum_j x[b,j,i] a[b,j,n]

#define BB 2
#define CC 32
#define NN 4096
#define EPSV 1e-5f

typedef short short8 __attribute__((ext_vector_type(8)));  // 8 bf16 (4 VGPRs)
typedef float f32x4 __attribute__((ext_vector_type(4)));

// ws float offsets
#define OFF_FNC  0          // bf16 f [B][N][C]   (131072 floats of storage)
#define OFF_FCN  131072     // bf16 f [B][C][N]   (131072)
#define OFF_M    262144     // f32 M[b][n]        (8192)
#define OFF_SC   270336     // BN scale           (32)
#define OFF_SH   270368     // BN shift           (32)
#define OFF_AA   270400     // aa[b][d][c]        (2048)
#define OFF_XW   272448     // xw[b][i][j]=x[b,j,i] (2048)
#define OFF_Z    274496     // f32 Z[b][n] atomic (8192)   [memset, then 1/Z]
#define OFF_EP   282688     // f32 ep[b][c][n]    (262144) [memset]
#define WS_FLOATS 544832

__device__ inline ushort f2bf(float x) {            // RNE f32->bf16
    uint u = __float_as_uint(x);
    uint r = u + 0x7FFFu + ((u >> 16) & 1u);
    return (ushort)(r >> 16);
}
__device__ inline float bf2f(ushort h) { return __uint_as_float(((uint)h) << 16); }
__device__ inline uint packbf(float lo, float hi) { // truncating pack (w>=0)
    return (__float_as_uint(hi) & 0xFFFF0000u) | (__float_as_uint(lo) >> 16);
}

// ---------- fused prologue: blocks 0..31 BN stats, blocks 32..95 aa ----------
__global__ void k_pre(const float* __restrict__ x, const float* __restrict__ gamma,
                      const float* __restrict__ bias, float* __restrict__ ws) {
    __shared__ float rs[4], rs2[4];
    __shared__ float red[4][CC];
    const int tid = threadIdx.x;
    const int w = tid >> 6, l = tid & 63;
    if (blockIdx.x < 32) {
        const int c = blockIdx.x;
        float s = 0.f, s2 = 0.f;
        for (int i = tid; i < BB * NN; i += 256) {
            const int b = i >> 12, n = i & (NN - 1);
            const float v = x[((size_t)(b * CC + c)) * NN + n];
            s += v; s2 += v * v;
        }
        for (int off = 32; off; off >>= 1) { s += __shfl_down(s, off); s2 += __shfl_down(s2, off); }
        if (l == 0) { rs[w] = s; rs2[w] = s2; }
        __syncthreads();
        if (tid == 0) {
            const float S = rs[0] + rs[1] + rs[2] + rs[3];
            const float S2 = rs2[0] + rs2[1] + rs2[2] + rs2[3];
            const float mean = S * (1.f / (BB * NN));
            const float var = S2 * (1.f / (BB * NN)) - mean * mean;  // biased
            const float sc = gamma[c] * rsqrtf(var + EPSV);
            ws[OFF_SC + c] = sc;
            ws[OFF_SH + c] = bias[c] - mean * sc;
        }
    } else {
        const int bid = blockIdx.x - 32;          // b*32+d
        const int b = bid >> 5, d = bid & 31;
        const float* xb = x + (size_t)b * CC * NN;
        float acc[CC];
        #pragma unroll
        for (int c = 0; c < CC; ++c) acc[c] = 0.f;
        for (int n = tid; n < NN; n += 256) {
            const float vd = xb[(size_t)d * NN + n];
            #pragma unroll
            for (int c = 0; c < CC; ++c) acc[c] += xb[(size_t)c * NN + n] * vd;
        }
        #pragma unroll
        for (int c = 0; c < CC; ++c) {
            float r = acc[c];
            for (int off = 32; off; off >>= 1) r += __shfl_down(r, off);
            if (l == 0) red[w][c] = r;
        }
        __syncthreads();
        if (tid < CC) ws[OFF_AA + ((size_t)(b * CC + d)) * CC + tid] =
            red[0][tid] + red[1][tid] + red[2][tid] + red[3][tid];
    }
}

// ---------- f = relu(bn(x)) -> bf16 in both layouts + M[n]=||f_n||^2 ----------
__global__ void k_makef(const float* __restrict__ x, float* __restrict__ ws) {
    const int idx = blockIdx.x * 256 + threadIdx.x;  // b*N+n, 8192 total
    const int b = idx >> 12, n = idx & (NN - 1);
    __shared__ float ssc[CC], ssh[CC];
    if (threadIdx.x < CC) { ssc[threadIdx.x] = ws[OFF_SC + threadIdx.x]; ssh[threadIdx.x] = ws[OFF_SH + threadIdx.x]; }
    __syncthreads();
    ushort* fnc = (ushort*)(ws + OFF_FNC) + (size_t)idx * CC;
    ushort* fcn = (ushort*)(ws + OFF_FCN);
    float msum = 0.f;
    #pragma unroll
    for (int c = 0; c < CC; ++c) {
        const float v = x[((size_t)(b * CC + c)) * NN + n];
        const float f = fmaxf(v * ssc[c] + ssh[c], 0.f);
        const ushort h = f2bf(f);
        const float fr = bf2f(h);
        msum += fr * fr;                       // diag of bf16-cb, fp32 acc
        fnc[c] = h;
        fcn[((size_t)(b * CC + c)) * NN + n] = h;
    }
    ws[OFF_M + idx] = msum;
}

// ---------- pass 1: Z[n] = sum_m exp(cb[m,n]-M[n]); block 512 does batch-softmax xw ----------
__global__ void __launch_bounds__(256) k_zpass(float* __restrict__ ws) {
    if (blockIdx.x == 512) {                  // CAM channel softmax over batch axis
        for (int t = threadIdx.x; t < CC * CC; t += 256) {
            const int i = t >> 5, j = t & 31;
            const float a0 = ws[OFF_AA + (0 * CC + j) * CC + i];
            const float a1 = ws[OFF_AA + (1 * CC + j) * CC + i];
            const float mx = fmaxf(a0, a1);   // aa ~ O(4096): max-sub mandatory
            const float e0 = __expf(a0 - mx), e1 = __expf(a1 - mx);
            const float inv = 1.f / (e0 + e1);
            ws[OFF_XW + (0 * CC + i) * CC + j] = e0 * inv;
            ws[OFF_XW + (1 * CC + i) * CC + j] = e1 * inv;
        }
        return;
    }
    const ushort* fnc = (const ushort*)(ws + OFF_FNC);
    const int bid = blockIdx.x;               // 0..511
    const int b   = bid >> 8;
    const int ng  = (bid >> 3) & 31;          // group of 128 n
    const int mch = bid & 7;                  // m-chunk of 512
    const int lane = threadIdx.x & 63;
    const int wv   = threadIdx.x >> 6;
    const int ml = lane & 15, kg = lane >> 4;
    const int nbA = ng * 128 + wv * 16;       // wave's two n-strips
    const int nbB = nbA + 64;
    const f32x4 zero = {0.f, 0.f, 0.f, 0.f};
    const short8 bfA = *(const short8*)(fnc + ((size_t)(b * NN + nbA + ml)) * CC + kg * 8);
    const short8 bfB = *(const short8*)(fnc + ((size_t)(b * NN + nbB + ml)) * CC + kg * 8);
    const float MA = ws[OFF_M + b * NN + nbA + ml];
    const float MB = ws[OFF_M + b * NN + nbB + ml];
    float zA = 0.f, zB = 0.f;
    const int m0 = mch * 512;
    for (int mm = m0; mm < m0 + 512; mm += 16) {
        const short8 af = *(const short8*)(fnc + ((size_t)(b * NN + mm + ml)) * CC + kg * 8);
        f32x4 dA = __builtin_amdgcn_mfma_f32_16x16x32_bf16(af, bfA, zero, 0, 0, 0);
        f32x4 dB = __builtin_amdgcn_mfma_f32_16x16x32_bf16(af, bfB, zero, 0, 0, 0);
        zA += __expf(dA[0] - MA) + __expf(dA[1] - MA) + __expf(dA[2] - MA) + __expf(dA[3] - MA);
        zB += __expf(dB[0] - MB) + __expf(dB[1] - MB) + __expf(dB[2] - MB) + __expf(dB[3] - MB);
    }
    zA += __shfl_xor(zA, 16); zA += __shfl_xor(zA, 32);
    zB += __shfl_xor(zB, 16); zB += __shfl_xor(zB, 32);
    if (lane < 16) {
        atomicAdd(ws + OFF_Z + b * NN + nbA + ml, zA);
        atomicAdd(ws + OFF_Z + b * NN + nbB + ml, zB);
    }
}

// ---------- Z -> 1/Z ----------
__global__ void k_zinv(float* __restrict__ ws) {
    const int i = blockIdx.x * 256 + threadIdx.x;   // 8192
    ws[OFF_Z + i] = 1.f / ws[OFF_Z + i];
}

// ---------- pass 2: e_p^T[c][m] += sum_n f[c,n] w[m,n] ----------
__global__ void __launch_bounds__(256) k_eppass(float* __restrict__ ws) {
    const ushort* fnc = (const ushort*)(ws + OFF_FNC);
    const ushort* fcn = (const ushort*)(ws + OFF_FCN);
    const int bid = blockIdx.x;               // 512
    const int b   = bid >> 8;
    const int mg  = (bid >> 2) & 63;
    const int nch = bid & 3;                  // n-chunk of 1024
    const int lane = threadIdx.x & 63;
    const int wv   = threadIdx.x >> 6;
    const int ml = lane & 15, kg = lane >> 4;
    const int mb = mg * 64 + wv * 16;         // wave's 16 output columns
    const f32x4 zero = {0.f, 0.f, 0.f, 0.f};
    // cb^T B-operand: cols = m (fixed for the whole wave)
    const short8 bm = *(const short8*)(fnc + ((size_t)(b * NN + mb + ml)) * CC + kg * 8);
    f32x4 acc0 = zero, acc1 = zero;           // e_p^T[c][m], c = kg*4+r (+16)
    const float* Mp  = ws + OFF_M + b * NN;
    const float* Zip = ws + OFF_Z + b * NN;   // holds 1/Z
    const int n0beg = nch * 1024;
    for (int n0 = n0beg; n0 < n0beg + 1024; n0 += 32) {
        // cb^T tiles: D[n-local][m-local]; lane holds 4 n-rows (kg*4+r), col=ml
        const short8 an0 = *(const short8*)(fnc + ((size_t)(b * NN + n0      + ml)) * CC + kg * 8);
        const short8 an1 = *(const short8*)(fnc + ((size_t)(b * NN + n0 + 16 + ml)) * CC + kg * 8);
        f32x4 d0 = __builtin_amdgcn_mfma_f32_16x16x32_bf16(an0, bm, zero, 0, 0, 0);
        f32x4 d1 = __builtin_amdgcn_mfma_f32_16x16x32_bf16(an1, bm, zero, 0, 0, 0);
        const float4 M0 = *(const float4*)(Mp  + n0 + kg * 4);
        const float4 M1 = *(const float4*)(Mp  + n0 + 16 + kg * 4);
        const float4 Z0 = *(const float4*)(Zip + n0 + kg * 4);
        const float4 Z1 = *(const float4*)(Zip + n0 + 16 + kg * 4);
        const float w00 = __expf(d0[0] - M0.x) * Z0.x;
        const float w01 = __expf(d0[1] - M0.y) * Z0.y;
        const float w02 = __expf(d0[2] - M0.z) * Z0.z;
        const float w03 = __expf(d0[3] - M0.w) * Z0.w;
        const float w10 = __expf(d1[0] - M1.x) * Z1.x;
        const float w11 = __expf(d1[1] - M1.y) * Z1.y;
        const float w12 = __expf(d1[2] - M1.z) * Z1.z;
        const float w13 = __expf(d1[3] - M1.w) * Z1.w;
        // packed pairs along n: p* from d0 (n-local kg*4+{0,1},{2,3}), q* from d1 (+16)
        const uint p0 = packbf(w00, w01), p1 = packbf(w02, w03);
        const uint q0 = packbf(w10, w11), q1 = packbf(w12, w13);
        // Redistribute into PV B-fragment: lane (kg,ml) needs n-local kg*8..kg*8+7, col=ml.
        // Sources are lanes {ml, ml+16, ml+32, ml+48} (same col).  8 shfl, no LDS.
        union { uint u[4]; short8 s; } wf;
        {
            const int s0 = (((kg & 1) << 1) + 0) * 16 + ml;
            const int s1 = (((kg & 1) << 1) + 1) * 16 + ml;
            const uint vp0 = __shfl(p0, s0), vp1 = __shfl(p1, s0);
            const uint vp2 = __shfl(p0, s1), vp3 = __shfl(p1, s1);
            const uint vq0 = __shfl(q0, s0), vq1 = __shfl(q1, s0);
            const uint vq2 = __shfl(q0, s1), vq3 = __shfl(q1, s1);
            const bool hi = (kg >= 2);
            wf.u[0] = hi ? vq0 : vp0; wf.u[1] = hi ? vq1 : vp1;
            wf.u[2] = hi ? vq2 : vp2; wf.u[3] = hi ? vq3 : vp3;
        }
        // PV: D2[c][m] += sum_n f[c,n] * w[m,n]
        const short8 a20 = *(const short8*)(fcn + ((size_t)(b * CC + ml))      * NN + n0 + kg * 8);
        const short8 a21 = *(const short8*)(fcn + ((size_t)(b * CC + 16 + ml)) * NN + n0 + kg * 8);
        acc0 = __builtin_amdgcn_mfma_f32_16x16x32_bf16(a20, wf.s, acc0, 0, 0, 0);
        acc1 = __builtin_amdgcn_mfma_f32_16x16x32_bf16(a21, wf.s, acc1, 0, 0, 0);
    }
    #pragma unroll
    for (int r = 0; r < 4; ++r) {
        atomicAdd(ws + OFF_EP + ((size_t)(b * CC + kg * 4 + r))      * NN + mb + ml, acc0[r]);
        atomicAdd(ws + OFF_EP + ((size_t)(b * CC + 16 + kg * 4 + r)) * NN + mb + ml, acc1[r]);
    }
}

// ---------- epilogue: out = alpha*e_p + beta*e_c + 2a ----------
__global__ void k_final(const float* __restrict__ x, const float* __restrict__ alpha_p,
                        const float* __restrict__ beta_p, const float* __restrict__ ws,
                        float* __restrict__ out) {
    const int idx = blockIdx.x * 128 + threadIdx.x;  // b*N + m
    const int b = idx >> 12, m = idx & (NN - 1);
    __shared__ float sxw[CC * CC];
    for (int i = threadIdx.x; i < CC * CC; i += 128)
        sxw[i] = ws[OFF_XW + b * CC * CC + i];
    __syncthreads();
    const float alpha = *alpha_p, beta = *beta_p;
    float ec[CC];
    #pragma unroll
    for (int c = 0; c < CC; ++c) ec[c] = 0.f;
    const float* xb = x + (size_t)b * CC * NN;
    #pragma unroll
    for (int j = 0; j < CC; ++j) {
        const float aj = xb[(size_t)j * NN + m];
        #pragma unroll
        for (int c = 0; c < CC; ++c) ec[c] += sxw[c * CC + j] * aj;
    }
    #pragma unroll
    for (int c = 0; c < CC; ++c) {
        const float av = xb[(size_t)c * NN + m];
        out[((size_t)(b * CC + c)) * NN + m] =
            alpha * ws[OFF_EP + ((size_t)(b * CC + c)) * NN + m] + beta * ec[c] + 2.f * av;
    }
}

extern "C" void kernel_launch(void* const* d_in, const int* in_sizes, int n_in,
                              void* d_out, int out_size, void* d_ws, size_t ws_size,
                              hipStream_t stream) {
    const float* x     = (const float*)d_in[0];
    const float* gamma = (const float*)d_in[1];
    const float* bias  = (const float*)d_in[2];
    const float* alpha = (const float*)d_in[3];
    const float* beta  = (const float*)d_in[4];
    float* out = (float*)d_out;
    float* ws  = (float*)d_ws;

    // zero only the atomic-accumulated regions (Z and EP are adjacent)
    hipMemsetAsync((char*)d_ws + (size_t)OFF_Z * 4, 0, (size_t)(8192 + 262144) * 4, stream);

    hipLaunchKernelGGL(k_pre,    dim3(96),  dim3(256), 0, stream, x, gamma, bias, ws);
    hipLaunchKernelGGL(k_makef,  dim3(32),  dim3(256), 0, stream, x, ws);
    hipLaunchKernelGGL(k_zpass,  dim3(513), dim3(256), 0, stream, ws);
    hipLaunchKernelGGL(k_zinv,   dim3(32),  dim3(256), 0, stream, ws);
    hipLaunchKernelGGL(k_eppass, dim3(512), dim3(256), 0, stream, ws);
    hipLaunchKernelGGL(k_final,  dim3(64),  dim3(128), 0, stream, x, alpha, beta, ws, out);
}